// Round 6
// baseline (244.162 us; speedup 1.0000x reference)
//
#include <hip/hip_runtime.h>
#include <hip/hip_bf16.h>
#include <stdint.h>

// B=2, T=2048, D=1024, H=16, hd=64.
// R6: attn 32 q-rows/wave + 48KB LDS (3 blocks/CU) + XCD swizzle; combine fused
// into outproj A-staging; qkv DMAs straight from x when input is bf16.

typedef unsigned short u16;
typedef short bf16x8 __attribute__((ext_vector_type(8)));
typedef float f32x4  __attribute__((ext_vector_type(4)));

#if defined(__has_builtin) && __has_builtin(__builtin_amdgcn_exp2f)
#define EXP2F(x) __builtin_amdgcn_exp2f(x)
#else
#define EXP2F(x) exp2f(x)
#endif

__device__ __forceinline__ u16 f2b(float f) {           // fp32 -> bf16 RNE
  uint32_t u = __float_as_uint(f);
  u += 0x7fffu + ((u >> 16) & 1u);
  return (u16)(u >> 16);
}
__device__ __forceinline__ uint32_t pkbf(float a, float b) {  // v_cvt_pk_bf16_f32
  __hip_bfloat162 h = __float22bfloat162_rn(make_float2(a, b));
  union { __hip_bfloat162 h2; uint32_t u; } cv; cv.h2 = h;
  return cv.u;
}

// async global->LDS DMA, 16B per lane. LDS dest must be uniform-base + lane*16.
__device__ __forceinline__ void gl2lds16(const void* g, void* l) {
  __builtin_amdgcn_global_load_lds(
      (const __attribute__((address_space(1))) unsigned int*)g,
      (__attribute__((address_space(3))) unsigned int*)l, 16, 0, 0);
}

// ---------------------------------------------------------------- dtype sniff
__global__ void sniff_kernel(const u16* x, int* flag) {
  __shared__ int cnt;
  if (threadIdx.x == 0) cnt = 0;
  __syncthreads();
  int c = 0;
  for (int i = threadIdx.x; i < 4096; i += 256) {
    float a = fabsf(__uint_as_float(((uint32_t)x[2*i]) << 16));
    if (a > 1e-3f && a < 100.f) c++;
  }
  atomicAdd(&cnt, c);
  __syncthreads();
  if (threadIdx.x == 0) *flag = (cnt > 2048) ? 1 : 0;
}

// ------------------------------------------------- 64x64 transpose helper
__device__ __forceinline__ void tr_tile(const void* src, u16* dst, int Kd, int N,
                                        int n0, int k0, int isb, u16* Lt, int tid)
{
  const int r = tid >> 2, cseg = (tid & 3) << 4;
  u16 t[16];
  if (isb) {
    const u16* s = (const u16*)src + (size_t)(k0 + r) * N + n0 + cseg;
    *(uint4*)&t[0] = *(const uint4*)s;
    *(uint4*)&t[8] = *(const uint4*)(s + 8);
  } else {
    const float* s = (const float*)src + (size_t)(k0 + r) * N + n0 + cseg;
    #pragma unroll
    for (int j = 0; j < 4; j++) {
      float4 v = *(const float4*)(s + j * 4);
      t[j*4+0] = f2b(v.x); t[j*4+1] = f2b(v.y); t[j*4+2] = f2b(v.z); t[j*4+3] = f2b(v.w);
    }
  }
  #pragma unroll
  for (int j = 0; j < 16; j++) Lt[(cseg + j) * 72 + r] = t[j];
  __syncthreads();
  const int n = tid >> 2, kseg = (tid & 3) << 4;
  uint4 u0 = *(const uint4*)&Lt[n * 72 + kseg];
  uint4 u1 = *(const uint4*)&Lt[n * 72 + kseg + 8];
  u16* d = dst + (size_t)(n0 + n) * Kd + k0 + kseg;
  *(uint4*)d = u0;
  *(uint4*)(d + 8) = u1;
}

// ------------------------------------------------- fused prep
// blocks [0,2048): x->bf16 (only if input fp32) ; [2048,2816): Wqkv^T ;
// [2816,3072): Wout^T ; [3072,3328): RoPE table CS[t*32+f] = {cos,sin}
__global__ __launch_bounds__(256) void prep_kernel(
    const void* __restrict__ x, const void* __restrict__ wqkv,
    const void* __restrict__ wout, const int* __restrict__ flag,
    u16* __restrict__ Xb, u16* __restrict__ Wqkvt, u16* __restrict__ Woutt,
    float2* __restrict__ CS)
{
  __shared__ u16 Lt[64 * 72];
  const int isb = *flag;
  const int bid = blockIdx.x, tid = threadIdx.x;
  if (bid < 2048) {
    if (isb) return;                    // qkv reads x directly in bf16 mode
    const size_t i = ((size_t)bid * 256 + tid) * 8;
    const float* s = (const float*)x + i;
    float4 a = *(const float4*)s, b = *(const float4*)(s + 4);
    uint4 p;
    p.x = pkbf(a.x, a.y); p.y = pkbf(a.z, a.w);
    p.z = pkbf(b.x, b.y); p.w = pkbf(b.z, b.w);
    *(uint4*)&Xb[i] = p;
  } else if (bid < 2816) {
    const int b = bid - 2048;
    tr_tile(wqkv, Wqkvt, 1024, 3072, (b % 48) * 64, (b / 48) * 64, isb, Lt, tid);
  } else if (bid < 3072) {
    const int b = bid - 2816;
    tr_tile(wout, Woutt, 1024, 1024, (b % 16) * 64, (b / 16) * 64, isb, Lt, tid);
  } else {
    const int idx = (bid - 3072) * 256 + tid;   // 65536
    const int t = idx >> 5, f = idx & 31;
    float invf = __expf(-(float)f * 0.2878231366242557f);  // ln(1e4)/32
    float th = (float)t * invf;
    float sn, cs;
    sincosf(th, &sn, &cs);
    CS[idx] = make_float2(cs, sn);
  }
}

// ------------------------------------------------- QKV GEMM (NT, bf16) + RoPE
__global__ __launch_bounds__(256) void qkv_kernel(
    const void* __restrict__ xraw, const u16* __restrict__ Xb,
    const u16* __restrict__ Wt, const int* __restrict__ flag,
    const float2* __restrict__ CS,
    u16* __restrict__ Q, u16* __restrict__ K, u16* __restrict__ Vt)
{
  __shared__ u16 As[128 * 64];
  __shared__ u16 Bs[128 * 64];
  const u16* Asrc = (*flag) ? (const u16*)xraw : Xb;   // uniform select
  const int tid = threadIdx.x;
  const int n0 = blockIdx.x * 128;
  const int m0 = blockIdx.y * 128;
  const int w = tid >> 6, l = tid & 63, lr = l & 15, lq = l >> 4;
  const int mrow0 = (w & 1) * 64;
  const int ncol0 = (w >> 1) * 64;
  const int srow = tid >> 3;
  const int gseg = (tid & 7) ^ (srow & 7);

  f32x4 acc[4][4] = {};

  for (int k0 = 0; k0 < 1024; k0 += 64) {
    __syncthreads();
    #pragma unroll
    for (int rd = 0; rd < 4; rd++) {
      const int row = srow + rd * 32;
      gl2lds16(Asrc + (size_t)(m0 + row) * 1024 + k0 + gseg * 8, &As[tid * 8 + rd * 2048]);
      gl2lds16(Wt + (size_t)(n0 + row) * 1024 + k0 + gseg * 8, &Bs[tid * 8 + rd * 2048]);
    }
    __syncthreads();
    #pragma unroll
    for (int kc = 0; kc < 2; kc++) {
      bf16x8 af[4], bf[4];
      #pragma unroll
      for (int i = 0; i < 4; i++) {
        const int seg = ((kc << 2) | lq) ^ (lr & 7);
        af[i] = *(const bf16x8*)&As[(mrow0 + i * 16 + lr) * 64 + seg * 8];
        bf[i] = *(const bf16x8*)&Bs[(ncol0 + i * 16 + lr) * 64 + seg * 8];
      }
      #pragma unroll
      for (int mb = 0; mb < 4; mb++)
        #pragma unroll
        for (int nb = 0; nb < 4; nb++)
          acc[mb][nb] = __builtin_amdgcn_mfma_f32_16x16x32_bf16(af[mb], bf[nb], acc[mb][nb], 0, 0, 0);
    }
  }

  const int col0 = n0 + ncol0;
  const int sec = col0 >> 10;            // 0=q 1=k 2=v
  const int h = (col0 >> 6) & 15;
  if (sec == 2) {
    #pragma unroll
    for (int mb = 0; mb < 4; mb++) {
      const int row0 = m0 + mrow0 + mb * 16 + lq * 4;
      const int b = row0 >> 11, t0 = row0 & 2047;
      #pragma unroll
      for (int nb = 0; nb < 4; nb++) {
        const int d = nb * 16 + lr;
        uint2 uv;
        uv.x = pkbf(acc[mb][nb][0], acc[mb][nb][1]);
        uv.y = pkbf(acc[mb][nb][2], acc[mb][nb][3]);
        *(uint2*)&Vt[(((size_t)b * 16 + h) * 64 + d) * 2048 + t0] = uv;
      }
    }
  } else {
    u16* dst = (sec == 0) ? Q : K;
    const float qscale = 0.125f * 1.44269504f;   // 1/sqrt(hd) * log2(e), q only
    #pragma unroll
    for (int mb = 0; mb < 4; mb++) {
      const int row0 = m0 + mrow0 + mb * 16 + lq * 4;
      const int b = row0 >> 11, t0 = row0 & 2047;
      #pragma unroll
      for (int nb = 0; nb < 4; nb++) {
        const int d = nb * 16 + lr;
        const int f = d & 31;
        #pragma unroll
        for (int r = 0; r < 4; r++) {
          const int t = t0 + r;
          float2 cs = CS[t * 32 + f];
          float val = acc[mb][nb][r];
          float prt = __shfl_xor(val, 1, 64);   // partner col d^1 = lane lr^1
          float res = fmaf(val, cs.x, ((d & 1) ? prt : -prt) * cs.y);
          if (sec == 0) res *= qscale;
          dst[(((size_t)b * 16 + h) * 2048 + t) * 64 + d] = f2b(res);
        }
      }
    }
  }
}

// ------------------------------------------------- MFMA flash attention (R6)
// Block = 4 waves x 32 q-rows = 128 rows of one (b,h). grid (512, ns).
// bh = blockIdx.x & 31 -> all q-tiles of one bh land on one XCD (L2 reuse).
// S^T = mfma(Kfrag, Qfrag) -> in-lane pack -> ds_write_b64 into swizzled P[m][s].
// Double-buffered K/V DMA, one barrier per 64-s tile. LDS 48KB -> 3 blocks/CU.
__global__ __launch_bounds__(256, 3) void attn_kernel(
    const u16* __restrict__ Q, const u16* __restrict__ K,
    const u16* __restrict__ Vt, u16* __restrict__ ATT,
    float* __restrict__ Op, float* __restrict__ Ls)
{
  __shared__ u16 Ks[2][64 * 64];    // 16 KB
  __shared__ u16 Vs[2][64 * 64];    // 16 KB
  __shared__ u16 Ps[4][32 * 64];    // 16 KB per-wave P, XOR-swizzled
  const int tid = threadIdx.x;
  const int w = tid >> 6, l = tid & 63, lr = l & 15, lq = l >> 4;
  const int bh = blockIdx.x & 31;
  const int qt = blockIdx.x >> 5;       // 0..15
  const int ns = gridDim.y, sh = blockIdx.y;
  const int slen = 2048 / ns;
  const int sbeg = sh * slen;
  const size_t base = (size_t)bh * (2048 * 64);
  const int qrow0 = qt * 128 + w * 32;
  u16* Psw = &Ps[w][0];

  // Q fragments (used as B-operand: col m = lane&15, k = quad*8+j)
  bf16x8 qf[2][2];
  #pragma unroll
  for (int mb = 0; mb < 2; mb++)
    #pragma unroll
    for (int kc = 0; kc < 2; kc++)
      qf[mb][kc] = *(const bf16x8*)(Q + base + (size_t)(qrow0 + mb * 16 + lr) * 64 + kc * 32 + lq * 8);

  f32x4 oa[4][2] = {};            // O^T: [db][mb]
  float2 ls2[2] = {};

  const int srow = tid >> 3;

  auto stage = [&](int buf, int s0) {
    #pragma unroll
    for (int rd = 0; rd < 2; rd++) {
      const int row = srow + rd * 32;
      const int gs = (tid & 7) ^ (row & 7);
      gl2lds16(K + base + (size_t)(s0 + row) * 64 + gs * 8, &Ks[buf][tid * 8 + rd * 2048]);
      gl2lds16(Vt + base + (size_t)row * 2048 + s0 + gs * 8, &Vs[buf][tid * 8 + rd * 2048]);
    }
  };

  stage(0, sbeg);
  const int nt = slen >> 6;

  #pragma unroll 1
  for (int t = 0; t < nt; t++) {
    const int buf = t & 1;
    __syncthreads();                       // drains DMA for buf, fences prev reads
    if (t + 1 < nt) stage(buf ^ 1, sbeg + (t + 1) * 64);

    bf16x8 kf[4][2], vf[4][2];
    #pragma unroll
    for (int nb = 0; nb < 4; nb++)
      #pragma unroll
      for (int kc = 0; kc < 2; kc++) {
        const int seg = ((kc << 2) | lq) ^ (lr & 7);
        kf[nb][kc] = *(const bf16x8*)&Ks[buf][(nb * 16 + lr) * 64 + seg * 8];
        vf[nb][kc] = *(const bf16x8*)&Vs[buf][(nb * 16 + lr) * 64 + seg * 8];
      }

    // S^T blocks: row s = sb*16+quad*4+r, col m = mb*16+lane&15
    #pragma unroll
    for (int sb = 0; sb < 4; sb++) {
      #pragma unroll
      for (int mb = 0; mb < 2; mb++) {
        f32x4 st = {};
        st = __builtin_amdgcn_mfma_f32_16x16x32_bf16(kf[sb][0], qf[mb][0], st, 0, 0, 0);
        st = __builtin_amdgcn_mfma_f32_16x16x32_bf16(kf[sb][1], qf[mb][1], st, 0, 0, 0);
        float e0 = EXP2F(st[0]), e1 = EXP2F(st[1]), e2 = EXP2F(st[2]), e3 = EXP2F(st[3]);
        ls2[mb].x += e0 + e2;
        ls2[mb].y += e1 + e3;
        uint2 pp;
        pp.x = pkbf(e0, e1);
        pp.y = pkbf(e2, e3);
        // P[m][s]: s = sb*16+lq*4, 16B-seg XOR swizzle: seg=(2sb+lq/2)^(m&7)
        const int pseg = ((sb << 1) | (lq >> 1)) ^ (lr & 7);
        *(uint2*)&Psw[(mb * 16 + lr) * 64 + pseg * 8 + (lq & 1) * 4] = pp;
      }
    }

    // O^T += V^T · P^T : A = Vt-frag (rows d), B = P^T (cols m), k = s
    #pragma unroll
    for (int mb = 0; mb < 2; mb++) {
      const int rs0 = lq ^ (lr & 7);
      const int rs1 = (4 | lq) ^ (lr & 7);
      bf16x8 pf0 = *(const bf16x8*)&Psw[(mb * 16 + lr) * 64 + rs0 * 8];
      bf16x8 pf1 = *(const bf16x8*)&Psw[(mb * 16 + lr) * 64 + rs1 * 8];
      #pragma unroll
      for (int db = 0; db < 4; db++) {
        oa[db][mb] = __builtin_amdgcn_mfma_f32_16x16x32_bf16(vf[db][0], pf0, oa[db][mb], 0, 0, 0);
        oa[db][mb] = __builtin_amdgcn_mfma_f32_16x16x32_bf16(vf[db][1], pf1, oa[db][mb], 0, 0, 0);
      }
    }
  }

  // reduce row sums across quads (lanes lr, lr+16, lr+32, lr+48)
  float lsum[2];
  #pragma unroll
  for (int mb = 0; mb < 2; mb++) {
    float v = ls2[mb].x + ls2[mb].y;
    v += __shfl_xor(v, 16, 64);
    v += __shfl_xor(v, 32, 64);
    lsum[mb] = v;
  }

  const int b = bh >> 4, h = bh & 15;
  if (ns == 1) {
    #pragma unroll
    for (int mb = 0; mb < 2; mb++) {
      const float inv = 1.f / lsum[mb];
      const int t = qrow0 + mb * 16 + lr;
      u16* dst = ATT + ((size_t)(b * 2048 + t)) * 1024 + h * 64;
      #pragma unroll
      for (int db = 0; db < 4; db++) {
        uint2 u;
        u.x = pkbf(oa[db][mb][0] * inv, oa[db][mb][1] * inv);
        u.y = pkbf(oa[db][mb][2] * inv, oa[db][mb][3] * inv);
        *(uint2*)&dst[db * 16 + lq * 4] = u;
      }
    }
  } else {
    float* op = Op + (size_t)sh * (65536ull * 64);
    #pragma unroll
    for (int mb = 0; mb < 2; mb++) {
      const size_t row = (size_t)bh * 2048 + qrow0 + mb * 16 + lr;
      #pragma unroll
      for (int db = 0; db < 4; db++)
        *(f32x4*)&op[row * 64 + db * 16 + lq * 4] = oa[db][mb];
      if (lq == 0) Ls[(size_t)sh * 65536 + row] = lsum[mb];
    }
  }
}

// ------------------------------------------------- output projection + fused combine
// A-tile built from the two fp32 s-split partials: (Op0+Op1) * 1/(Ls0+Ls1),
// packed to bf16 and written into the same XOR-swizzled LDS layout the MFMA
// loop expects. B-tile (Wout^T) still staged by DMA.
__global__ __launch_bounds__(256) void outproj2_kernel(
    const float* __restrict__ Op, const float* __restrict__ Ls,
    const u16* __restrict__ Wt, const int* __restrict__ flag,
    void* __restrict__ outv)
{
  __shared__ u16 As[128 * 64];
  __shared__ u16 Bs[128 * 64];
  const int isb = *flag;
  const int tid = threadIdx.x;
  const int n0 = blockIdx.x * 128;
  const int m0 = blockIdx.y * 128;
  const int w = tid >> 6, l = tid & 63, lr = l & 15, lq = l >> 4;
  const int mrow0 = (w & 1) * 64;
  const int ncol0 = (w >> 1) * 64;
  const int srow = tid >> 3;
  const int gseg = (tid & 7) ^ (srow & 7);
  const int rloc = tid >> 1, hf = tid & 1;
  const int grow = m0 + rloc;                 // 0..4095
  const int gb = grow >> 11, gt = grow & 2047;

  f32x4 acc[4][4] = {};

  for (int k0 = 0; k0 < 1024; k0 += 64) {
    const int h = k0 >> 6;
    __syncthreads();
    #pragma unroll
    for (int rd = 0; rd < 4; rd++) {
      const int row = srow + rd * 32;
      gl2lds16(Wt + (size_t)(n0 + row) * 1024 + k0 + gseg * 8, &Bs[tid * 8 + rd * 2048]);
    }
    {
      const size_t RR = ((size_t)(gb * 16 + h)) * 2048 + gt;
      const float inv = 1.f / (Ls[RR] + Ls[65536 + RR]);
      const float* p0 = Op + RR * 64 + hf * 32;
      const float* p1 = p0 + 65536ull * 64;
      #pragma unroll
      for (int j = 0; j < 4; j++) {
        f32x4 a0 = *(const f32x4*)(p0 + j * 8);
        f32x4 a1 = *(const f32x4*)(p0 + j * 8 + 4);
        f32x4 b0 = *(const f32x4*)(p1 + j * 8);
        f32x4 b1 = *(const f32x4*)(p1 + j * 8 + 4);
        uint4 u;
        u.x = pkbf((a0[0] + b0[0]) * inv, (a0[1] + b0[1]) * inv);
        u.y = pkbf((a0[2] + b0[2]) * inv, (a0[3] + b0[3]) * inv);
        u.z = pkbf((a1[0] + b1[0]) * inv, (a1[1] + b1[1]) * inv);
        u.w = pkbf((a1[2] + b1[2]) * inv, (a1[3] + b1[3]) * inv);
        const int g = hf * 4 + j;
        *(uint4*)&As[rloc * 64 + (g ^ (rloc & 7)) * 8] = u;
      }
    }
    __syncthreads();
    #pragma unroll
    for (int kc = 0; kc < 2; kc++) {
      bf16x8 af[4], bf[4];
      #pragma unroll
      for (int i = 0; i < 4; i++) {
        const int seg = ((kc << 2) | lq) ^ (lr & 7);
        af[i] = *(const bf16x8*)&As[(mrow0 + i * 16 + lr) * 64 + seg * 8];
        bf[i] = *(const bf16x8*)&Bs[(ncol0 + i * 16 + lr) * 64 + seg * 8];
      }
      #pragma unroll
      for (int mb = 0; mb < 4; mb++)
        #pragma unroll
        for (int nb = 0; nb < 4; nb++)
          acc[mb][nb] = __builtin_amdgcn_mfma_f32_16x16x32_bf16(af[mb], bf[nb], acc[mb][nb], 0, 0, 0);
    }
  }
  #pragma unroll
  for (int mb = 0; mb < 4; mb++) {
    const int row = m0 + mrow0 + mb * 16 + lq * 4;
    #pragma unroll
    for (int nb = 0; nb < 4; nb++) {
      const int col = n0 + ncol0 + nb * 16 + lr;
      #pragma unroll
      for (int r = 0; r < 4; r++) {
        float val = acc[mb][nb][r];
        if (isb) ((u16*)outv)[(size_t)(row + r) * 1024 + col] = f2b(val);
        else     ((float*)outv)[(size_t)(row + r) * 1024 + col] = val;
      }
    }
  }
}

// ------------------------------------------------- output projection (ns=1 path)
__global__ __launch_bounds__(256) void outproj_kernel(
    const u16* __restrict__ A, const u16* __restrict__ Wt,
    const int* __restrict__ flag, void* __restrict__ outv)
{
  __shared__ u16 As[128 * 64];
  __shared__ u16 Bs[128 * 64];
  const int isb = *flag;
  const int tid = threadIdx.x;
  const int n0 = blockIdx.x * 128;
  const int m0 = blockIdx.y * 128;
  const int w = tid >> 6, l = tid & 63, lr = l & 15, lq = l >> 4;
  const int mrow0 = (w & 1) * 64;
  const int ncol0 = (w >> 1) * 64;
  const int srow = tid >> 3;
  const int gseg = (tid & 7) ^ (srow & 7);

  f32x4 acc[4][4] = {};

  for (int k0 = 0; k0 < 1024; k0 += 64) {
    __syncthreads();
    #pragma unroll
    for (int rd = 0; rd < 4; rd++) {
      const int row = srow + rd * 32;
      gl2lds16(A + (size_t)(m0 + row) * 1024 + k0 + gseg * 8, &As[tid * 8 + rd * 2048]);
      gl2lds16(Wt + (size_t)(n0 + row) * 1024 + k0 + gseg * 8, &Bs[tid * 8 + rd * 2048]);
    }
    __syncthreads();
    #pragma unroll
    for (int kc = 0; kc < 2; kc++) {
      bf16x8 af[4], bf[4];
      #pragma unroll
      for (int i = 0; i < 4; i++) {
        const int seg = ((kc << 2) | lq) ^ (lr & 7);
        af[i] = *(const bf16x8*)&As[(mrow0 + i * 16 + lr) * 64 + seg * 8];
        bf[i] = *(const bf16x8*)&Bs[(ncol0 + i * 16 + lr) * 64 + seg * 8];
      }
      #pragma unroll
      for (int mb = 0; mb < 4; mb++)
        #pragma unroll
        for (int nb = 0; nb < 4; nb++)
          acc[mb][nb] = __builtin_amdgcn_mfma_f32_16x16x32_bf16(af[mb], bf[nb], acc[mb][nb], 0, 0, 0);
    }
  }
  #pragma unroll
  for (int mb = 0; mb < 4; mb++) {
    const int row = m0 + mrow0 + mb * 16 + lq * 4;
    #pragma unroll
    for (int nb = 0; nb < 4; nb++) {
      const int col = n0 + ncol0 + nb * 16 + lr;
      #pragma unroll
      for (int r = 0; r < 4; r++) {
        float val = acc[mb][nb][r];
        if (isb) ((u16*)outv)[(size_t)(row + r) * 1024 + col] = f2b(val);
        else     ((float*)outv)[(size_t)(row + r) * 1024 + col] = val;
      }
    }
  }
}

extern "C" void kernel_launch(void* const* d_in, const int* in_sizes, int n_in,
                              void* d_out, int out_size, void* d_ws, size_t ws_size,
                              hipStream_t stream)
{
  const void* x    = d_in[0];
  const void* wqkv = d_in[1];
  const void* wout = d_in[2];
  char* ws = (char*)d_ws;
  const size_t MB = 1024 * 1024;
  int*    flag   = (int*)ws;
  float2* CS     = (float2*)(ws + 1024);            // 512 KB
  u16*    Xb     = (u16*)(ws + 1 * MB);             // 8 MB  (aliased by ATT)
  u16*    ATT    = Xb;
  u16*    Wqkvt  = (u16*)(ws + 9 * MB);             // 6 MB
  u16*    Woutt  = (u16*)(ws + 15 * MB);            // 2 MB
  u16*    Q      = (u16*)(ws + 17 * MB);            // 8 MB
  u16*    K      = (u16*)(ws + 25 * MB);            // 8 MB
  u16*    Vt     = (u16*)(ws + 33 * MB);            // 8 MB
  float*  Op     = (float*)(ws + 41 * MB);          // 32 MB (ns=2)
  float*  Ls     = (float*)(ws + 75 * MB);          // 0.5 MB

  const bool split = ws_size >= 76 * MB;            // deterministic across calls
  const int ns = split ? 2 : 1;

  sniff_kernel<<<1, 256, 0, stream>>>((const u16*)x, flag);
  prep_kernel<<<3328, 256, 0, stream>>>(x, wqkv, wout, flag, Xb, Wqkvt, Woutt, CS);
  qkv_kernel<<<dim3(24, 32), 256, 0, stream>>>(x, Xb, Wqkvt, flag, CS, Q, K, Vt);
  attn_kernel<<<dim3(512, ns), 256, 0, stream>>>(Q, K, Vt, ATT, Op, Ls);
  if (split)
    outproj2_kernel<<<dim3(8, 32), 256, 0, stream>>>(Op, Ls, Woutt, flag, d_out);
  else
    outproj_kernel<<<dim3(8, 32), 256, 0, stream>>>(ATT, Woutt, flag, d_out);
}